// Round 8
// baseline (1475.742 us; speedup 1.0000x reference)
//
#include <hip/hip_runtime.h>
#include <hip/hip_bf16.h>

// Problem constants (from reference)
#define NU 200000
#define NI 100000
#define DIM 64
#define NE 3200000

// Established (R0-R7):
//  - ALL float inputs are f32; edges int32, dict order (R7's device detector
//    evaluated all-f32/no-swap: output bit-identical to R6).
//  - OUTPUT IS F32 (reference output dtype, per harness contract). The
//    "(bf16, ...)" in the test label is a literal f-string; the traceback
//    shows all branches of _read_out, not the taken one. Writing bf16
//    explains the deterministic decorrelated errors of R4/R6/R7 exactly
//    (f32 read of packed bf16 pairs = stride-2 scramble of correct values).
//  - Output order: users first, then items.

__device__ __forceinline__ int iclamp(int x, int lo, int hi) {
    return x < lo ? lo : (x > hi ? hi : x);
}

__global__ void zero_i32_kernel(int* __restrict__ p, long long n) {
    long long i = (long long)blockIdx.x * blockDim.x + threadIdx.x;
    long long stride = (long long)gridDim.x * blockDim.x;
    for (; i < n; i += stride) p[i] = 0;
}

// flag: [3]=edge_swap  [10]=maxA [11]=maxB  (validated in R7)
__global__ void edge_detect_kernel(const int* __restrict__ a, const int* __restrict__ b,
                                   int n, int* __restrict__ flag) {
    int i = blockIdx.x * blockDim.x + threadIdx.x;
    int stride = gridDim.x * blockDim.x;
    int ma = 0, mb = 0;
    for (; i < n; i += stride) {
        ma = max(ma, a[i]);
        mb = max(mb, b[i]);
    }
    #pragma unroll
    for (int d = 32; d > 0; d >>= 1) {
        ma = max(ma, __shfl_down(ma, d, 64));
        mb = max(mb, __shfl_down(mb, d, 64));
    }
    if ((threadIdx.x & 63) == 0) {
        atomicMax(&flag[10], ma);
        atomicMax(&flag[11], mb);
    }
}
__global__ void finalize_kernel(int* __restrict__ flag) {
    if (threadIdx.x == 0 && blockIdx.x == 0) {
        int ma = flag[10], mb = flag[11];
        flag[3] = (mb >= NI && ma < NI) ? 1 : 0;
    }
}

// ---------------------------------------------------------------------------
// Zero the f32 output (harness poisons it with 0xAA before timed launches).
// ---------------------------------------------------------------------------
__global__ void zero_f32_kernel(float* __restrict__ p, long long n) {
    long long i = (long long)blockIdx.x * blockDim.x + threadIdx.x;
    long long stride = (long long)gridDim.x * blockDim.x;
    for (; i < n; i += stride) p[i] = 0.0f;
}

// ---------------------------------------------------------------------------
// One wave per edge, lane = dim. f32 atomic accumulate directly into d_out.
// atomicAdd on global f32 is device-scope (cross-XCD safe).
// ---------------------------------------------------------------------------
__global__ __launch_bounds__(256) void edge_atomic_kernel(
        const int* __restrict__ a, const int* __restrict__ b,
        const int* __restrict__ flag,
        const float* __restrict__ ev,
        const float* __restrict__ uemb, const float* __restrict__ iemb,
        float* __restrict__ outU, float* __restrict__ outI) {
    int sw = flag[3];
    const int* eu = sw ? b : a;
    const int* ei = sw ? a : b;
    long long t = (long long)blockIdx.x * blockDim.x + threadIdx.x;
    int lane = (int)(t & 63);
    long long e = t >> 6;
    if (e >= NE) return;
    int u = iclamp(eu[e], 0, NU - 1);
    int i = iclamp(ei[e], 0, NI - 1);
    float v  = ev[e];
    float xu = uemb[(size_t)u * DIM + lane];
    float xi = iemb[(size_t)i * DIM + lane];
    atomicAdd(&outU[(size_t)u * DIM + lane], v * xi);
    atomicAdd(&outI[(size_t)i * DIM + lane], v * xu);
}

// ===========================================================================
extern "C" void kernel_launch(void* const* d_in, const int* in_sizes, int n_in,
                              void* d_out, int out_size, void* d_ws, size_t ws_size,
                              hipStream_t stream) {
    // Identify embedding slots by element count (insurance against slot swap).
    const float* user_emb = (const float*)d_in[0];
    const float* item_emb = (const float*)d_in[1];
    if (in_sizes[0] == NI * DIM && in_sizes[1] == NU * DIM) {
        user_emb = (const float*)d_in[1];
        item_emb = (const float*)d_in[0];
    }
    const int*   edge_a   = (const int*)d_in[2];
    const int*   edge_b   = (const int*)d_in[3];
    const float* edge_val = (const float*)d_in[4];

    float* out = (float*)d_out;                 // F32 output (the R8 fix)
    float* out_users = out;                     // users first
    float* out_items = out + (size_t)NU * DIM;

    const long long NOUT = (long long)(NU + NI) * DIM;   // 19.2M f32

    int* flag = (int*)d_ws;   // 16 ints

    // Edge-order detector (validated R7; cheap insurance).
    zero_i32_kernel<<<1, 64, 0, stream>>>(flag, 16);
    edge_detect_kernel<<<512, 256, 0, stream>>>(edge_a, edge_b, NE, flag);
    finalize_kernel<<<1, 64, 0, stream>>>(flag);

    // Zero output (poisoned 0xAA before every timed launch), then accumulate.
    zero_f32_kernel<<<2048, 256, 0, stream>>>(out, NOUT);
    long long nthreads = (long long)NE * 64;
    edge_atomic_kernel<<<(int)(nthreads / 256), 256, 0, stream>>>(
        edge_a, edge_b, flag, edge_val, user_emb, item_emb, out_users, out_items);
}